// Round 1
// baseline (176.790 us; speedup 1.0000x reference)
//
#include <hip/hip_runtime.h>

// DyGFormer co-occurrence encoder, collapsed:
//   counts are per-batch histograms; the 2-layer MLP of a scalar count is a
//   513-entry lookup table T'[c] = relu(c*W1+b1)@W2 + b2 (b2 folded in).
//   out_src[b,l,:] = T'[hist_src[sid]] + T'[hist_dst[sid]]   (sid==0 -> c=0)
//   out_dst[b,l,:] = T'[hist_src[did]] + T'[hist_dst[did]]
// Memory-bound on the 134 MB fp32 output write.

#define BB      256
#define LL      512
#define DD      128
#define NNODES  1024
#define CMAX    512            // max possible count (L occurrences)
#define SPLITS  4              // row-splits per batch -> 1024 blocks
#define ROWS_PER (LL / SPLITS) // 128

// T'[c][e] = b2[e] + sum_d relu(c*W1[d]+b1[d]) * W2[d*D+e]
__global__ __launch_bounds__(DD) void build_table_kernel(
    const float* __restrict__ W1, const float* __restrict__ b1,
    const float* __restrict__ W2, const float* __restrict__ b2,
    float* __restrict__ T) {
  const int c = blockIdx.x;   // 0..CMAX
  const int e = threadIdx.x;  // 0..127
  __shared__ float h[DD];
  h[e] = fmaxf((float)c * W1[e] + b1[e], 0.0f);
  __syncthreads();
  float acc = b2[e];
#pragma unroll 8
  for (int d = 0; d < DD; ++d) acc = fmaf(h[d], W2[d * DD + e], acc);
  T[c * DD + e] = acc;
}

__global__ __launch_bounds__(256) void encode_kernel(
    const int* __restrict__ src_ids, const int* __restrict__ dst_ids,
    const float* __restrict__ T, float* __restrict__ out) {
  const int batch = blockIdx.x >> 2;           // blockIdx / SPLITS
  const int split = blockIdx.x & (SPLITS - 1);
  const int tid   = threadIdx.x;

  __shared__ int hist[2 * NNODES];   // [0..1023]=src hist, [1024..2047]=dst hist
  __shared__ int cnt[4 * ROWS_PER];  // c_src0,c_src1,c_dst0,c_dst1 for this split

  for (int i = tid; i < 2 * NNODES; i += 256) hist[i] = 0;
  __syncthreads();

  const int* sb = src_ids + batch * LL;
  const int* db = dst_ids + batch * LL;
  for (int i = tid; i < LL; i += 256) {
    atomicAdd(&hist[sb[i]], 1);
    atomicAdd(&hist[NNODES + db[i]], 1);
  }
  __syncthreads();

  const int r0 = split * ROWS_PER;
  if (tid < ROWS_PER) {
    const int sid = sb[r0 + tid];
    const int did = db[r0 + tid];
    cnt[tid]                = sid ? hist[sid] : 0;
    cnt[ROWS_PER + tid]     = sid ? hist[NNODES + sid] : 0;
    cnt[2 * ROWS_PER + tid] = did ? hist[did] : 0;
    cnt[3 * ROWS_PER + tid] = did ? hist[NNODES + did] : 0;
  }
  __syncthreads();

  // 128-float rows as 32 float4; 256 threads = 8 rows in flight per iter.
  const int lane = tid & 31;   // float4 index within the row
  const int rsub = tid >> 5;   // 0..7
  const size_t base    = ((size_t)batch * LL + r0) * DD;
  const size_t OUT_OFF = (size_t)BB * LL * DD;  // dst_feat offset in d_out

  for (int rr = rsub; rr < ROWS_PER; rr += 8) {
    const float4 a = ((const float4*)(T + (size_t)cnt[rr] * DD))[lane];
    const float4 b = ((const float4*)(T + (size_t)cnt[ROWS_PER + rr] * DD))[lane];
    float4 v; v.x = a.x + b.x; v.y = a.y + b.y; v.z = a.z + b.z; v.w = a.w + b.w;
    ((float4*)(out + base + (size_t)rr * DD))[lane] = v;
  }
  for (int rr = rsub; rr < ROWS_PER; rr += 8) {
    const float4 a = ((const float4*)(T + (size_t)cnt[2 * ROWS_PER + rr] * DD))[lane];
    const float4 b = ((const float4*)(T + (size_t)cnt[3 * ROWS_PER + rr] * DD))[lane];
    float4 v; v.x = a.x + b.x; v.y = a.y + b.y; v.z = a.z + b.z; v.w = a.w + b.w;
    ((float4*)(out + OUT_OFF + base + (size_t)rr * DD))[lane] = v;
  }
}

extern "C" void kernel_launch(void* const* d_in, const int* in_sizes, int n_in,
                              void* d_out, int out_size, void* d_ws, size_t ws_size,
                              hipStream_t stream) {
  const int*   src = (const int*)d_in[0];
  const int*   dst = (const int*)d_in[1];
  const float* W1  = (const float*)d_in[2];  // (1, D)
  const float* b1  = (const float*)d_in[3];  // (D,)
  const float* W2  = (const float*)d_in[4];  // (D, D) row-major
  const float* b2  = (const float*)d_in[5];  // (D,)
  float* out = (float*)d_out;
  float* T   = (float*)d_ws;  // (CMAX+1) * D floats = 263 KB

  build_table_kernel<<<CMAX + 1, DD, 0, stream>>>(W1, b1, W2, b2, T);
  encode_kernel<<<BB * SPLITS, 256, 0, stream>>>(src, dst, T, out);
}

// Round 3
// 157.335 us; speedup vs baseline: 1.1237x; 1.1237x over previous
//
#include <hip/hip_runtime.h>

// DyGFormer co-occurrence encoder, collapsed:
//   counts are per-batch histograms; the 2-layer MLP of a scalar count is a
//   513-entry lookup table T'[c] = relu(c*W1+b1)@W2 + b2 (b2 folded in).
//   out_src[b,l,:] = T'[hist_src[sid]] + T'[hist_dst[sid]]   (sid==0 -> c=0)
//   out_dst[b,l,:] = T'[hist_src[did]] + T'[hist_dst[did]]
// Memory-bound on the 134 MB fp32 output write (floor ~21 us at 6.3 TB/s).

#define BB      256
#define LL      512
#define DD      128
#define NNODES  1024
#define CMAX    512            // max possible count
#define SPLITS  4              // row-splits per batch -> 1024 blocks (4/CU)
#define ROWS_PER (LL / SPLITS) // 128

typedef float f4x __attribute__((ext_vector_type(4)));  // native vec: NT-store OK

// T'[c][e] = b2[e] + sum_d relu(c*W1[d]+b1[d]) * W2[d*D+e]
__global__ __launch_bounds__(DD) void build_table_kernel(
    const float* __restrict__ W1, const float* __restrict__ b1,
    const float* __restrict__ W2, const float* __restrict__ b2,
    float* __restrict__ T) {
  const int c = blockIdx.x;   // 0..CMAX
  const int e = threadIdx.x;  // 0..127
  __shared__ float h[DD];
  h[e] = fmaxf((float)c * W1[e] + b1[e], 0.0f);
  __syncthreads();
  float acc = b2[e];
#pragma unroll 16
  for (int d = 0; d < DD; ++d) acc = fmaf(h[d], W2[d * DD + e], acc);
  T[c * DD + e] = acc;
}

__global__ __launch_bounds__(256) void encode_kernel(
    const int* __restrict__ src_ids, const int* __restrict__ dst_ids,
    const float* __restrict__ T, float* __restrict__ out) {
  const int batch = blockIdx.x >> 2;           // blockIdx / SPLITS
  const int split = blockIdx.x & (SPLITS - 1);
  const int tid   = threadIdx.x;

  __shared__ int hist[2 * NNODES];   // [0..1023]=src hist, [1024..2047]=dst hist
  __shared__ int cnt[4 * ROWS_PER];  // cA,cB (for src out), cC,cD (for dst out)

#pragma unroll
  for (int i = tid; i < 2 * NNODES; i += 256) hist[i] = 0;
  __syncthreads();

  const int* sb = src_ids + batch * LL;
  const int* db = dst_ids + batch * LL;
#pragma unroll
  for (int i = tid; i < LL; i += 256) {
    atomicAdd(&hist[sb[i]], 1);
    atomicAdd(&hist[NNODES + db[i]], 1);
  }
  __syncthreads();

  const int r0 = split * ROWS_PER;
  if (tid < ROWS_PER) {
    const int sid = sb[r0 + tid];
    const int did = db[r0 + tid];
    cnt[tid]                = sid ? hist[sid] : 0;
    cnt[ROWS_PER + tid]     = sid ? hist[NNODES + sid] : 0;
    cnt[2 * ROWS_PER + tid] = did ? hist[did] : 0;
    cnt[3 * ROWS_PER + tid] = did ? hist[NNODES + did] : 0;
  }
  __syncthreads();

  // 128-float rows as 32 f4x; 8 rows in flight per iteration of 256 thr.
  const int lane = tid & 31;   // f4x index within the row
  const int rsub = tid >> 5;   // 0..7
  float* out_s = out + ((size_t)batch * LL + r0) * DD;
  float* out_d = out_s + (size_t)BB * LL * DD;  // dst_feat region

#pragma unroll 4
  for (int rr = rsub; rr < ROWS_PER; rr += 8) {
    const f4x a = ((const f4x*)(T + (size_t)cnt[rr] * DD))[lane];
    const f4x b = ((const f4x*)(T + (size_t)cnt[ROWS_PER + rr] * DD))[lane];
    const f4x c = ((const f4x*)(T + (size_t)cnt[2 * ROWS_PER + rr] * DD))[lane];
    const f4x d = ((const f4x*)(T + (size_t)cnt[3 * ROWS_PER + rr] * DD))[lane];
    const f4x vs = a + b;
    const f4x vd = c + d;
    __builtin_nontemporal_store(vs, ((f4x*)(out_s + (size_t)rr * DD)) + lane);
    __builtin_nontemporal_store(vd, ((f4x*)(out_d + (size_t)rr * DD)) + lane);
  }
}

extern "C" void kernel_launch(void* const* d_in, const int* in_sizes, int n_in,
                              void* d_out, int out_size, void* d_ws, size_t ws_size,
                              hipStream_t stream) {
  const int*   src = (const int*)d_in[0];
  const int*   dst = (const int*)d_in[1];
  const float* W1  = (const float*)d_in[2];  // (1, D)
  const float* b1  = (const float*)d_in[3];  // (D,)
  const float* W2  = (const float*)d_in[4];  // (D, D) row-major
  const float* b2  = (const float*)d_in[5];  // (D,)
  float* out = (float*)d_out;
  float* T   = (float*)d_ws;  // (CMAX+1) * D floats = 263 KB

  build_table_kernel<<<CMAX + 1, DD, 0, stream>>>(W1, b1, W2, b2, T);
  encode_kernel<<<BB * SPLITS, 256, 0, stream>>>(src, dst, T, out);
}